// Round 7
// baseline (102.768 us; speedup 1.0000x reference)
//
#include <hip/hip_runtime.h>

typedef __attribute__((ext_vector_type(8))) short bf16x8;
typedef __attribute__((ext_vector_type(4))) float f32x4;

constexpr int N_PTS = 16384;
constexpr int KN = 16;    // neighbors
constexpr int P  = 15;    // kernel points
constexpr int CI = 64;
constexpr int CO = 128;
constexpr int QB = 16;    // query points per agg block
constexpr int KTOT   = P * CI;     // 960 (k = p*64 + c, natural order)
constexpr int KSTEPS = KTOT / 32;  // 30
// ws layout: WB fragments [0, 245760); agg bf16 [N][960] at byte 262144 (31.5 MB)
constexpr size_t AGG_OFF = 262144;

static __device__ __forceinline__ unsigned short f2bf(float f) {
    unsigned u = __float_as_uint(f);
    u = (u + 0x7fffu + ((u >> 16) & 1u)) >> 16;  // RNE
    return (unsigned short)u;
}

static __device__ __forceinline__ void gload16(const void* g, void* l) {
    __builtin_amdgcn_global_load_lds(
        (const __attribute__((address_space(1))) unsigned*)g,
        (__attribute__((address_space(3))) unsigned*)l, 16, 0, 0);
}

// ---- Prep: W fp32 [P][CI][CO] -> bf16 B-fragments WB[kstep][ntile][lane][8]
// k = p*64 + c  =>  W[p][c][o] = W[k*CO + o] directly.
__global__ __launch_bounds__(256) void prep_w(const float* __restrict__ W,
                                              unsigned short* __restrict__ WB) {
    const int t = blockIdx.x * 256 + threadIdx.x;   // 30*8*64 = 15360 total
    const int l  = t & 63;
    const int k0 = (t >> 9) * 32 + ((l >> 4) * 8);  // kstep*32 + quarter*8
    const int o  = ((t >> 6) & 7) * 16 + (l & 15);  // ntile*16 + col
    unsigned short v[8];
    #pragma unroll
    for (int j = 0; j < 8; ++j) v[j] = f2bf(W[(size_t)(k0 + j) * CO + o]);
    uint4 q;
    q.x = v[0] | ((unsigned)v[1] << 16);
    q.y = v[2] | ((unsigned)v[3] << 16);
    q.z = v[4] | ((unsigned)v[5] << 16);
    q.w = v[6] | ((unsigned)v[7] << 16);
    *(uint4*)&WB[(size_t)t * 8] = q;
}

// ---- Kernel A+B: influences + neighbor aggregation -> agg bf16 [N][960] ----
__global__ __launch_bounds__(256) void kpconv_agg(
    const float* __restrict__ query,    // [N][3]
    const float* __restrict__ support,  // [M][3]
    const int*   __restrict__ nidx,     // [N][KN]
    const float* __restrict__ feats,    // [M][CI]
    const float* __restrict__ kp,       // [P][3]
    unsigned short* __restrict__ aggG)  // [N][KTOT]
{
    __shared__ float sKp[P][3];
    __shared__ int   sIdx[QB][KN];
    __shared__ __align__(16) float sInfl[QB][KN][16];   // 16 KB

    const int t  = threadIdx.x;
    const int n0 = blockIdx.x * QB;

    if (t < P * 3) ((float*)sKp)[t] = kp[t];
    __syncthreads();

    // ---- Phase A: one thread per (pt, k) ----
    {
        const int pt = t >> 4, k = t & 15;
        const int n = n0 + pt;
        const int idx = nidx[n * KN + k];
        sIdx[pt][k] = idx;
        const float rx = support[idx * 3 + 0] - query[n * 3 + 0];
        const float ry = support[idx * 3 + 1] - query[n * 3 + 1];
        const float rz = support[idx * 3 + 2] - query[n * 3 + 2];
        #pragma unroll
        for (int p = 0; p < P; ++p) {
            const float dx = rx - sKp[p][0];
            const float dy = ry - sKp[p][1];
            const float dz = rz - sKp[p][2];
            sInfl[pt][k][p] = fmaxf(1.0f - sqrtf(dx*dx + dy*dy + dz*dz), 0.0f);
        }
        sInfl[pt][k][15] = 0.0f;
    }
    __syncthreads();

    // ---- Phase B: thread (pt = t>>4, c = (t&15)*4) -> agg[n][p*64 + c..c+3]
    {
        const int pt = t >> 4;
        const int c  = (t & 15) * 4;
        int idxv[KN];
        {
            const int4* ip = (const int4*)sIdx[pt];
            #pragma unroll
            for (int k4 = 0; k4 < 4; ++k4) {
                const int4 v = ip[k4];
                idxv[k4*4+0] = v.x; idxv[k4*4+1] = v.y;
                idxv[k4*4+2] = v.z; idxv[k4*4+3] = v.w;
            }
        }
        float acc[P][4];
        #pragma unroll
        for (int p = 0; p < P; ++p)
            #pragma unroll
            for (int j = 0; j < 4; ++j) acc[p][j] = 0.0f;

        #pragma unroll
        for (int k = 0; k < KN; ++k) {
            const float4 f = *(const float4*)&feats[(size_t)idxv[k] * CI + c];
            float iv[16];
            {
                const float4* ip = (const float4*)sInfl[pt][k];  // broadcast
                *(float4*)&iv[0]  = ip[0];
                *(float4*)&iv[4]  = ip[1];
                *(float4*)&iv[8]  = ip[2];
                *(float4*)&iv[12] = ip[3];
            }
            #pragma unroll
            for (int p = 0; p < P; ++p) {
                acc[p][0] = fmaf(iv[p], f.x, acc[p][0]);
                acc[p][1] = fmaf(iv[p], f.y, acc[p][1]);
                acc[p][2] = fmaf(iv[p], f.z, acc[p][2]);
                acc[p][3] = fmaf(iv[p], f.w, acc[p][3]);
            }
        }
        const size_t rowBase = (size_t)(n0 + pt) * KTOT;
        #pragma unroll
        for (int p = 0; p < P; ++p) {
            uint2 w;
            w.x = f2bf(acc[p][0]) | ((unsigned)f2bf(acc[p][1]) << 16);
            w.y = f2bf(acc[p][2]) | ((unsigned)f2bf(acc[p][3]) << 16);
            *(uint2*)&aggG[rowBase + p * CI + c] = w;   // 128B per 16 lanes
        }
    }
}

// ---- Kernel C: out[16384][128] = agg[16384][960] @ W[960][128] ----
// 256 blocks x 512 thr (8 waves), BM=64. A staged ONCE into LDS in
// fragment-major order (conflict-free ds_read_b128); no barriers in K-loop.
__global__ __launch_bounds__(512) void kpconv_gemm(
    const unsigned short* __restrict__ aggG,  // bf16 [N][KTOT]
    const unsigned short* __restrict__ WB,    // [kstep][ntile][64][8]
    float* __restrict__ out)                  // [N][CO]
{
    // sA content: [g = s*4 + rt][lane][8 shorts], g in [0,120)  => 122880 B
    __shared__ __align__(16) unsigned short sA[KSTEPS * 4 * 64 * 8];

    const int t = threadIdx.x;
    const int w = t >> 6, l = t & 63;
    const int n0 = blockIdx.x * 64;

    // ---- stage A-panel: 7680 chunks of 16B; thread t takes chunks t+i*512.
    // Per wave-issue, g = chunk>>6 is uniform; per-lane global src scattered.
    #pragma unroll
    for (int i = 0; i < 15; ++i) {
        const int chunk = i * 512 + t;
        const int g  = chunk >> 6;          // wave-uniform: i*8 + w
        const int cl = chunk & 63;          // = l
        const int s  = g >> 2, rt = g & 3;
        const unsigned short* src =
            aggG + (size_t)(n0 + rt * 16 + (cl & 15)) * KTOT + s * 32 + ((cl >> 4) * 8);
        gload16(src, &sA[(size_t)chunk * 8]);
    }
    __syncthreads();   // vmcnt(0) drain -> panel resident

    // wave w owns rows (w&1)*32..+32 (row-tiles rh,rh+1), cols (w>>1)*32..+32
    const int rh = (w & 1) * 2;
    const int nh = (w >> 1) * 2;
    f32x4 acc00 = {0.f,0.f,0.f,0.f}, acc01 = {0.f,0.f,0.f,0.f};
    f32x4 acc10 = {0.f,0.f,0.f,0.f}, acc11 = {0.f,0.f,0.f,0.f};

    #pragma unroll 3
    for (int s = 0; s < KSTEPS; ++s) {
        const bf16x8 a0 = *(const bf16x8*)&sA[((s * 4 + rh    ) * 64 + l) * 8];
        const bf16x8 a1 = *(const bf16x8*)&sA[((s * 4 + rh + 1) * 64 + l) * 8];
        const bf16x8 b0 = *(const bf16x8*)&WB[((size_t)(s * 8 + nh    ) * 64 + l) * 8];
        const bf16x8 b1 = *(const bf16x8*)&WB[((size_t)(s * 8 + nh + 1) * 64 + l) * 8];
        acc00 = __builtin_amdgcn_mfma_f32_16x16x32_bf16(a0, b0, acc00, 0, 0, 0);
        acc01 = __builtin_amdgcn_mfma_f32_16x16x32_bf16(a0, b1, acc01, 0, 0, 0);
        acc10 = __builtin_amdgcn_mfma_f32_16x16x32_bf16(a1, b0, acc10, 0, 0, 0);
        acc11 = __builtin_amdgcn_mfma_f32_16x16x32_bf16(a1, b1, acc11, 0, 0, 0);
    }

    // ---- epilogue: C/D layout col=l&15, row=(l>>4)*4+r ----
    const int col0 = (w >> 1) * 32 + (l & 15);
    const int row0 = n0 + (w & 1) * 32 + (l >> 4) * 4;
    #pragma unroll
    for (int r = 0; r < 4; ++r) {
        out[(size_t)(row0 + r) * CO + col0]           = acc00[r];
        out[(size_t)(row0 + r) * CO + col0 + 16]      = acc01[r];
        out[(size_t)(row0 + 16 + r) * CO + col0]      = acc10[r];
        out[(size_t)(row0 + 16 + r) * CO + col0 + 16] = acc11[r];
    }
}

extern "C" void kernel_launch(void* const* d_in, const int* in_sizes, int n_in,
                              void* d_out, int out_size, void* d_ws, size_t ws_size,
                              hipStream_t stream) {
    const float* query   = (const float*)d_in[0];
    const float* support = (const float*)d_in[1];
    const int*   nidx    = (const int*)d_in[2];
    const float* feats   = (const float*)d_in[3];
    const float* W       = (const float*)d_in[4];
    const float* kp      = (const float*)d_in[5];
    float* out = (float*)d_out;

    unsigned short* WB   = (unsigned short*)d_ws;
    unsigned short* aggG = (unsigned short*)((char*)d_ws + AGG_OFF);

    hipLaunchKernelGGL(prep_w, dim3(60), dim3(256), 0, stream, W, WB);
    hipLaunchKernelGGL(kpconv_agg, dim3(N_PTS / QB), dim3(256), 0, stream,
                       query, support, nidx, feats, kp, aggG);
    hipLaunchKernelGGL(kpconv_gemm, dim3(N_PTS / 64), dim3(512), 0, stream,
                       aggG, WB, out);
}

// Round 8
// 90.666 us; speedup vs baseline: 1.1335x; 1.1335x over previous
//
#include <hip/hip_runtime.h>

typedef __attribute__((ext_vector_type(8))) short bf16x8;
typedef __attribute__((ext_vector_type(4))) float f32x4;

constexpr int N_PTS = 16384;
constexpr int KN = 16;    // neighbors
constexpr int P  = 15;    // kernel points
constexpr int CI = 64;
constexpr int CO = 128;
constexpr int QB = 16;    // query points per block
constexpr int KTOT   = P * CI;     // 960
constexpr int KSTEPS = KTOT / 32;  // 30
constexpr int NTILES = CO / 16;    // 8
constexpr int AGG_PITCH = KTOT + 8; // 968 shorts/row
constexpr int PF = 4;              // B-prefetch depth (registers)

static __device__ __forceinline__ unsigned short f2bf(float f) {
    unsigned u = __float_as_uint(f);
    u = (u + 0x7fffu + ((u >> 16) & 1u)) >> 16;  // RNE
    return (unsigned short)u;
}

// ---- Prep: W (fp32 [P][CI][CO]) -> bf16 B-fragments WB[kstep][ntile][lane][8]
__global__ __launch_bounds__(256) void prep_w(const float* __restrict__ W,
                                              unsigned short* __restrict__ WB) {
    const int t = blockIdx.x * 256 + threadIdx.x;   // 30*8*64 = 15360 total
    const int l  = t & 63;
    const int kb = (t >> 9) * 32 + ((l >> 4) * 8);
    const int o  = ((t >> 6) & 7) * 16 + (l & 15);
    unsigned short v[8];
    #pragma unroll
    for (int j = 0; j < 8; ++j) v[j] = f2bf(W[(size_t)(kb + j) * CO + o]);
    uint4 q;
    q.x = v[0] | ((unsigned)v[1] << 16);
    q.y = v[2] | ((unsigned)v[3] << 16);
    q.z = v[4] | ((unsigned)v[5] << 16);
    q.w = v[6] | ((unsigned)v[7] << 16);
    *(uint4*)&WB[(size_t)t * 8] = q;
}

__global__ __launch_bounds__(256) void kpconv_main(
    const float* __restrict__ query,    // [N][3]
    const float* __restrict__ support,  // [M][3]
    const int*   __restrict__ nidx,     // [N][KN]
    const float* __restrict__ feats,    // [M][CI]
    const unsigned short* __restrict__ WB, // bf16 fragments
    const float* __restrict__ kp,       // [P][3]
    float* __restrict__ out)            // [N][CO]
{
    __shared__ float sKp[P][3];
    __shared__ int   sIdx[QB][KN];
    __shared__ __align__(16) float sInfl[QB][KN][16];            // 16 KB
    __shared__ __align__(16) unsigned short sAgg[QB][AGG_PITCH]; // ~30.3 KB

    const int t  = threadIdx.x;
    const int n0 = blockIdx.x * QB;

    if (t < P * 3) ((float*)sKp)[t] = kp[t];
    __syncthreads();

    // ---- Phase A: one thread per (pt, k) ----
    {
        const int pt = t >> 4, k = t & 15;
        const int n = n0 + pt;
        const int idx = nidx[n * KN + k];
        sIdx[pt][k] = idx;
        const float rx = support[idx * 3 + 0] - query[n * 3 + 0];
        const float ry = support[idx * 3 + 1] - query[n * 3 + 1];
        const float rz = support[idx * 3 + 2] - query[n * 3 + 2];
        #pragma unroll
        for (int p = 0; p < P; ++p) {
            const float dx = rx - sKp[p][0];
            const float dy = ry - sKp[p][1];
            const float dz = rz - sKp[p][2];
            sInfl[pt][k][p] = fmaxf(1.0f - sqrtf(dx*dx + dy*dy + dz*dz), 0.0f);
        }
        sInfl[pt][k][15] = 0.0f;
    }
    __syncthreads();

    // ---- Phase B: thread (pt = t>>4, c = (t&15)*4); agg[pt][p][c..c+3] ----
    {
        const int pt = t >> 4;
        const int c  = (t & 15) * 4;
        int idxv[KN];
        {
            const int4* ip = (const int4*)sIdx[pt];
            #pragma unroll
            for (int k4 = 0; k4 < 4; ++k4) {
                const int4 v = ip[k4];
                idxv[k4*4+0] = v.x; idxv[k4*4+1] = v.y;
                idxv[k4*4+2] = v.z; idxv[k4*4+3] = v.w;
            }
        }
        float acc[P][4];
        #pragma unroll
        for (int p = 0; p < P; ++p)
            #pragma unroll
            for (int j = 0; j < 4; ++j) acc[p][j] = 0.0f;

        #pragma unroll
        for (int k = 0; k < KN; ++k) {
            const float4 f = *(const float4*)&feats[(size_t)idxv[k] * CI + c];
            float iv[16];
            {
                const float4* ip = (const float4*)sInfl[pt][k];  // broadcast reads
                *(float4*)&iv[0]  = ip[0];
                *(float4*)&iv[4]  = ip[1];
                *(float4*)&iv[8]  = ip[2];
                *(float4*)&iv[12] = ip[3];
            }
            #pragma unroll
            for (int p = 0; p < P; ++p) {
                acc[p][0] = fmaf(iv[p], f.x, acc[p][0]);
                acc[p][1] = fmaf(iv[p], f.y, acc[p][1]);
                acc[p][2] = fmaf(iv[p], f.z, acc[p][2]);
                acc[p][3] = fmaf(iv[p], f.w, acc[p][3]);
            }
        }
        #pragma unroll
        for (int p = 0; p < P; ++p) {
            uint2 w;
            w.x = f2bf(acc[p][0]) | ((unsigned)f2bf(acc[p][1]) << 16);
            w.y = f2bf(acc[p][2]) | ((unsigned)f2bf(acc[p][3]) << 16);
            *(uint2*)&sAgg[pt][p * CI + c] = w;
        }
    }
    __syncthreads();

    // ---- Phase C: wave w -> ntiles 2w, 2w+1; fully unrolled K-loop with
    // register B-prefetch depth PF=4 (8 loads in flight, no per-step stall).
    {
        const int w = t >> 6, l = t & 63;
        const int row = l & 15;
        const int kq  = (l >> 4) * 8;
        f32x4 c0 = {0.f, 0.f, 0.f, 0.f};
        f32x4 c1 = {0.f, 0.f, 0.f, 0.f};
        const unsigned short* aggRow = &sAgg[row][kq];
        const unsigned short* wb0 = &WB[(size_t)(2 * w * 64 + l) * 8];
        // WB strides: kstep = NTILES*64*8 = 4096 shorts, ntile = 512 shorts.
        bf16x8 pb0[PF], pb1[PF];
        #pragma unroll
        for (int s = 0; s < PF; ++s) {
            pb0[s] = *(const bf16x8*)&wb0[(size_t)s * 4096];
            pb1[s] = *(const bf16x8*)&wb0[(size_t)s * 4096 + 512];
        }
        #pragma unroll
        for (int s = 0; s < KSTEPS; ++s) {
            const bf16x8 a = *(const bf16x8*)&aggRow[s * 32];
            c0 = __builtin_amdgcn_mfma_f32_16x16x32_bf16(a, pb0[s & (PF - 1)], c0, 0, 0, 0);
            c1 = __builtin_amdgcn_mfma_f32_16x16x32_bf16(a, pb1[s & (PF - 1)], c1, 0, 0, 0);
            if (s + PF < KSTEPS) {
                pb0[s & (PF - 1)] = *(const bf16x8*)&wb0[(size_t)(s + PF) * 4096];
                pb1[s & (PF - 1)] = *(const bf16x8*)&wb0[(size_t)(s + PF) * 4096 + 512];
            }
        }
        const int rbase = (l >> 4) * 4;
        const int o0 = 2 * w * 16 + (l & 15);
        #pragma unroll
        for (int r = 0; r < 4; ++r) {
            const int pt = rbase + r;
            out[(size_t)(n0 + pt) * CO + o0]      = c0[r];
            out[(size_t)(n0 + pt) * CO + o0 + 16] = c1[r];
        }
    }
}

extern "C" void kernel_launch(void* const* d_in, const int* in_sizes, int n_in,
                              void* d_out, int out_size, void* d_ws, size_t ws_size,
                              hipStream_t stream) {
    const float* query   = (const float*)d_in[0];
    const float* support = (const float*)d_in[1];
    const int*   nidx    = (const int*)d_in[2];
    const float* feats   = (const float*)d_in[3];
    const float* W       = (const float*)d_in[4];
    const float* kp      = (const float*)d_in[5];
    float* out = (float*)d_out;
    unsigned short* WB = (unsigned short*)d_ws;   // 245760 B

    hipLaunchKernelGGL(prep_w, dim3(60), dim3(256), 0, stream, W, WB);
    hipLaunchKernelGGL(kpconv_main, dim3(N_PTS / QB), dim3(256), 0, stream,
                       query, support, nidx, feats, WB, kp, out);
}

// Round 9
// 86.244 us; speedup vs baseline: 1.1916x; 1.0513x over previous
//
#include <hip/hip_runtime.h>

typedef __attribute__((ext_vector_type(8))) short bf16x8;
typedef __attribute__((ext_vector_type(4))) float f32x4;

constexpr int N_PTS = 16384;
constexpr int KN = 16;    // neighbors
constexpr int P  = 15;    // kernel points
constexpr int CI = 64;
constexpr int CO = 128;
constexpr int QB = 32;    // query points per block
constexpr int KTOT   = P * CI;     // 960
constexpr int KSTEPS = KTOT / 32;  // 30
constexpr int APITCH = KTOT + 8;   // 968 shorts/row; stride 1936B = 16 mod 128 -> 2-way max
constexpr int PF = 4;              // B-prefetch depth

static __device__ __forceinline__ unsigned short f2bf(float f) {
    unsigned u = __float_as_uint(f);
    u = (u + 0x7fffu + ((u >> 16) & 1u)) >> 16;  // RNE
    return (unsigned short)u;
}
#define BFLO(u) __uint_as_float((unsigned)(u) << 16)
#define BFHI(u) __uint_as_float((unsigned)(u) & 0xFFFF0000u)

// ---- Prep: W (fp32 [P][CI][CO]) -> bf16 B-fragments WB[kstep][ntile][lane][8]
__global__ __launch_bounds__(256) void prep_w(const float* __restrict__ W,
                                              unsigned short* __restrict__ WB) {
    const int t = blockIdx.x * 256 + threadIdx.x;   // 30*8*64 = 15360 total
    const int l  = t & 63;
    const int kb = (t >> 9) * 32 + ((l >> 4) * 8);
    const int o  = ((t >> 6) & 7) * 16 + (l & 15);
    unsigned short v[8];
    #pragma unroll
    for (int j = 0; j < 8; ++j) v[j] = f2bf(W[(size_t)(kb + j) * CO + o]);
    uint4 q;
    q.x = v[0] | ((unsigned)v[1] << 16);
    q.y = v[2] | ((unsigned)v[3] << 16);
    q.z = v[4] | ((unsigned)v[5] << 16);
    q.w = v[6] | ((unsigned)v[7] << 16);
    *(uint4*)&WB[(size_t)t * 8] = q;
}

__global__ __launch_bounds__(512, 4) void kpconv_main(
    const float* __restrict__ query,    // [N][3]
    const float* __restrict__ support,  // [M][3]
    const int*   __restrict__ nidx,     // [N][KN]
    const float* __restrict__ feats,    // [M][CI]
    const unsigned short* __restrict__ WB,
    const float* __restrict__ kp,       // [P][3]
    float* __restrict__ out)            // [N][CO]
{
    __shared__ float sKp[P][3];                                   // 180 B
    __shared__ unsigned short sIdxS[QB][KN];                      // 1 KB
    __shared__ int sCnt[QB];                                      // 128 B
    __shared__ unsigned char sKlist[QB][KN];                      // 512 B
    __shared__ __align__(16) unsigned short sInflB[QB][KN][16];   // 16 KB
    __shared__ __align__(16) unsigned short sAgg[QB][APITCH];     // 60.5 KB

    const int t  = threadIdx.x;
    const int n0 = blockIdx.x * QB;
    const int w  = t >> 6, l = t & 63;

    if (t < P * 3) ((float*)sKp)[t] = kp[t];
    if (t < QB) sCnt[t] = 0;
    __syncthreads();

    // ---- Phase A: thread (pt = t>>4, k = t&15); compact active k's ----
    {
        const int pt = t >> 4, k = t & 15;
        const int n = n0 + pt;
        const int idx = nidx[n * KN + k];
        sIdxS[pt][k] = (unsigned short)idx;
        const float rx = support[idx * 3 + 0] - query[n * 3 + 0];
        const float ry = support[idx * 3 + 1] - query[n * 3 + 1];
        const float rz = support[idx * 3 + 2] - query[n * 3 + 2];
        unsigned short h[16];
        float mx = 0.0f;
        #pragma unroll
        for (int p = 0; p < P; ++p) {
            const float dx = rx - sKp[p][0];
            const float dy = ry - sKp[p][1];
            const float dz = rz - sKp[p][2];
            const float infl = fmaxf(1.0f - sqrtf(dx*dx + dy*dy + dz*dz), 0.0f);
            mx = fmaxf(mx, infl);
            h[p] = f2bf(infl);
        }
        h[15] = 0;
        uint4 u0, u1;
        u0.x = h[0] | ((unsigned)h[1] << 16);   u0.y = h[2] | ((unsigned)h[3] << 16);
        u0.z = h[4] | ((unsigned)h[5] << 16);   u0.w = h[6] | ((unsigned)h[7] << 16);
        u1.x = h[8] | ((unsigned)h[9] << 16);   u1.y = h[10] | ((unsigned)h[11] << 16);
        u1.z = h[12] | ((unsigned)h[13] << 16); u1.w = h[14];
        *(uint4*)&sInflB[pt][k][0] = u0;
        *(uint4*)&sInflB[pt][k][8] = u1;
        if (mx > 0.0f) {
            const int slot = atomicAdd(&sCnt[pt], 1);
            sKlist[pt][slot] = (unsigned char)k;
        }
    }
    __syncthreads();

    // ---- Phase B: thread (pt = t>>4, c = (t&15)*4); only active k ----
    {
        const int pt = t >> 4;
        const int c  = (t & 15) * 4;
        const int nk = sCnt[pt];
        f32x4 A0={0,0,0,0},A1={0,0,0,0},A2={0,0,0,0},A3={0,0,0,0},A4={0,0,0,0};
        f32x4 A5={0,0,0,0},A6={0,0,0,0},A7={0,0,0,0},A8={0,0,0,0},A9={0,0,0,0};
        f32x4 A10={0,0,0,0},A11={0,0,0,0},A12={0,0,0,0},A13={0,0,0,0},A14={0,0,0,0};
        for (int i = 0; i < nk; ++i) {
            const int k   = sKlist[pt][i];
            const int idx = sIdxS[pt][k];
            const f32x4 fv = *(const f32x4*)&feats[(size_t)idx * CI + c];
            const uint4 u0 = *(const uint4*)&sInflB[pt][k][0];   // LDS broadcast
            const uint4 u1 = *(const uint4*)&sInflB[pt][k][8];
            A0  += BFLO(u0.x) * fv;  A1  += BFHI(u0.x) * fv;
            A2  += BFLO(u0.y) * fv;  A3  += BFHI(u0.y) * fv;
            A4  += BFLO(u0.z) * fv;  A5  += BFHI(u0.z) * fv;
            A6  += BFLO(u0.w) * fv;  A7  += BFHI(u0.w) * fv;
            A8  += BFLO(u1.x) * fv;  A9  += BFHI(u1.x) * fv;
            A10 += BFLO(u1.y) * fv;  A11 += BFHI(u1.y) * fv;
            A12 += BFLO(u1.z) * fv;  A13 += BFHI(u1.z) * fv;
            A14 += BFLO(u1.w) * fv;
        }
        #define STORE_P(p, Ap)                                                  \
            do {                                                                \
                uint2 wv;                                                       \
                wv.x = f2bf(Ap.x) | ((unsigned)f2bf(Ap.y) << 16);               \
                wv.y = f2bf(Ap.z) | ((unsigned)f2bf(Ap.w) << 16);               \
                *(uint2*)&sAgg[pt][(p) * CI + c] = wv;                          \
            } while (0)
        STORE_P(0, A0);  STORE_P(1, A1);  STORE_P(2, A2);  STORE_P(3, A3);
        STORE_P(4, A4);  STORE_P(5, A5);  STORE_P(6, A6);  STORE_P(7, A7);
        STORE_P(8, A8);  STORE_P(9, A9);  STORE_P(10, A10); STORE_P(11, A11);
        STORE_P(12, A12); STORE_P(13, A13); STORE_P(14, A14);
        #undef STORE_P
    }
    __syncthreads();

    // ---- Phase C: wave w -> ntile w, rows 0..31 (two 16-row tiles) ----
    {
        f32x4 c0 = {0.f, 0.f, 0.f, 0.f};
        f32x4 c1 = {0.f, 0.f, 0.f, 0.f};
        const int kq = (l >> 4) * 8;
        const unsigned short* a0 = &sAgg[l & 15][kq];
        const unsigned short* a1 = &sAgg[16 + (l & 15)][kq];
        const unsigned short* wb = &WB[(size_t)(w * 64 + l) * 8];  // kstep stride 4096
        bf16x8 pb[PF];
        #pragma unroll
        for (int s = 0; s < PF; ++s) pb[s] = *(const bf16x8*)&wb[(size_t)s * 4096];
        #pragma unroll
        for (int s = 0; s < KSTEPS; ++s) {
            const bf16x8 av0 = *(const bf16x8*)&a0[s * 32];
            const bf16x8 av1 = *(const bf16x8*)&a1[s * 32];
            const bf16x8 bv = pb[s & (PF - 1)];
            c0 = __builtin_amdgcn_mfma_f32_16x16x32_bf16(av0, bv, c0, 0, 0, 0);
            c1 = __builtin_amdgcn_mfma_f32_16x16x32_bf16(av1, bv, c1, 0, 0, 0);
            if (s + PF < KSTEPS) pb[s & (PF - 1)] = *(const bf16x8*)&wb[(size_t)(s + PF) * 4096];
        }
        const int o0 = w * 16 + (l & 15);
        const int r0 = n0 + (l >> 4) * 4;
        #pragma unroll
        for (int r = 0; r < 4; ++r) {
            out[(size_t)(r0 + r) * CO + o0]      = c0[r];
            out[(size_t)(r0 + 16 + r) * CO + o0] = c1[r];
        }
    }
}

extern "C" void kernel_launch(void* const* d_in, const int* in_sizes, int n_in,
                              void* d_out, int out_size, void* d_ws, size_t ws_size,
                              hipStream_t stream) {
    const float* query   = (const float*)d_in[0];
    const float* support = (const float*)d_in[1];
    const int*   nidx    = (const int*)d_in[2];
    const float* feats   = (const float*)d_in[3];
    const float* W       = (const float*)d_in[4];
    const float* kp      = (const float*)d_in[5];
    float* out = (float*)d_out;
    unsigned short* WB = (unsigned short*)d_ws;   // 245760 B

    hipLaunchKernelGGL(prep_w, dim3(60), dim3(256), 0, stream, W, WB);
    hipLaunchKernelGGL(kpconv_main, dim3(N_PTS / QB), dim3(512), 0, stream,
                       query, support, nidx, feats, WB, kp, out);
}